// Round 1
// baseline (480.076 us; speedup 1.0000x reference)
//
#include <hip/hip_runtime.h>

typedef unsigned short u16;
typedef __attribute__((ext_vector_type(4))) float    f32x4;
typedef __attribute__((ext_vector_type(8))) __bf16   bf16x8;
typedef __attribute__((ext_vector_type(8))) unsigned short u16x8;
typedef __attribute__((ext_vector_type(4))) unsigned short u16x4;
typedef __attribute__((ext_vector_type(4))) float    float4v;

#define MFMA16(a,b,c) __builtin_amdgcn_mfma_f32_16x16x32_bf16((a),(b),(c),0,0,0)

__device__ __forceinline__ u16 f2b(float f){
  union { float f; unsigned u; } v; v.f = f;
  return (u16)((v.u + 0x7fffu + ((v.u >> 16) & 1u)) >> 16);
}

__device__ __forceinline__ void gload_lds16(const void* g, void* l){
  __builtin_amdgcn_global_load_lds(
      (const __attribute__((address_space(1))) void*)g,
      (__attribute__((address_space(3))) void*)l, 16, 0, 0);
}

// ---------------- cast fp32 -> bf16 (elementwise, vectorized) ----------------
__global__ void cast_f32_bf16(const float* __restrict__ in, u16* __restrict__ out, int n4){
  int i = blockIdx.x * blockDim.x + threadIdx.x;
  int st = gridDim.x * blockDim.x;
  for (; i < n4; i += st){
    float4v v = ((const float4v*)in)[i];
    u16x4 o;
    o[0] = f2b(v[0]); o[1] = f2b(v[1]); o[2] = f2b(v[2]); o[3] = f2b(v[3]);
    ((u16x4*)out)[i] = o;
  }
}

// ------------- transpose + cast: src fp32 [R][C] -> dst bf16 [C][R] ----------
__global__ void tcast(const float* __restrict__ src, u16* __restrict__ dst, int R, int C){
  __shared__ float tile[32][33];
  int tx = threadIdx.x, ty = threadIdx.y;
  int c0 = blockIdx.x * 32, r0 = blockIdx.y * 32;
  #pragma unroll
  for (int i = 0; i < 4; i++)
    tile[ty + i*8][tx] = src[(long)(r0 + ty + i*8) * C + c0 + tx];
  __syncthreads();
  #pragma unroll
  for (int i = 0; i < 4; i++)
    dst[(long)(c0 + ty + i*8) * R + r0 + tx] = f2b(tile[tx][ty + i*8]);
}

// ---------------- bf16 GEMM: C = A[M,K] @ Bt[N,K]^T, 128x128 tile -----------
// MODE 0: scatter epilogue -> per-head q(,*0.125)/k/v bf16 buffers
// MODE 1: fp32 out + bias
template<int MODE>
__global__ __launch_bounds__(256, 2) void gemm_bt(
    const u16* __restrict__ A, const u16* __restrict__ Bt,
    int M, int N, int K,
    float* __restrict__ outF, const float* __restrict__ bias,
    u16* __restrict__ qb, u16* __restrict__ kb, u16* __restrict__ vb)
{
  __shared__ u16 a_lds[128*32];
  __shared__ u16 b_lds[128*32];
  const int t  = threadIdx.x;
  const int l  = t & 63;
  const int w  = t >> 6;
  const int wm = w >> 1, wn = w & 1;
  const int lr = l & 15, lg = l >> 4;
  const long mbase = (long)blockIdx.x * 128;
  const long nbase = (long)blockIdx.y * 128;

  f32x4 z = {0.f, 0.f, 0.f, 0.f};
  f32x4 acc[4][4];
  #pragma unroll
  for (int i = 0; i < 4; i++)
    #pragma unroll
    for (int j = 0; j < 4; j++) acc[i][j] = z;

  const int sr = t >> 2;          // staging row 0..63
  const int sc = (t & 3) * 8;     // staging col (elems)
  const u16* Ab = A  + mbase * K;
  const u16* Bb = Bt + nbase * K;

  for (int k0 = 0; k0 < K; k0 += 32){
    __syncthreads();
    gload_lds16(Ab + (long)sr      * K + k0 + sc, &a_lds[t*8]);
    gload_lds16(Ab + (long)(sr+64) * K + k0 + sc, &a_lds[2048 + t*8]);
    gload_lds16(Bb + (long)sr      * K + k0 + sc, &b_lds[t*8]);
    gload_lds16(Bb + (long)(sr+64) * K + k0 + sc, &b_lds[2048 + t*8]);
    __syncthreads();

    bf16x8 af[4], bfr[4];
    #pragma unroll
    for (int i = 0; i < 4; i++)
      af[i] = *(const bf16x8*)&a_lds[(wm*64 + i*16 + lr)*32 + lg*8];
    #pragma unroll
    for (int j = 0; j < 4; j++)
      bfr[j] = *(const bf16x8*)&b_lds[(wn*64 + j*16 + lr)*32 + lg*8];
    #pragma unroll
    for (int i = 0; i < 4; i++)
      #pragma unroll
      for (int j = 0; j < 4; j++)
        acc[i][j] = MFMA16(af[i], bfr[j], acc[i][j]);
  }

  if (MODE == 0){
    #pragma unroll
    for (int i = 0; i < 4; i++){
      #pragma unroll
      for (int j = 0; j < 4; j++){
        int col   = (int)nbase + wn*64 + j*16 + lr;
        int which = col >> 10;
        int h     = (col >> 6) & 15;
        int d     = col & 63;
        u16* dst  = (which == 0) ? qb : ((which == 1) ? kb : vb);
        float scl = (which == 0) ? 0.125f : 1.0f;
        #pragma unroll
        for (int r = 0; r < 4; r++){
          int m  = (int)mbase + wm*64 + i*16 + lg*4 + r;
          int b  = m >> 11, ns = m & 2047;
          dst[((long)((b << 4) + h) * 2048 + ns) * 64 + d] = f2b(acc[i][j][r] * scl);
        }
      }
    }
  } else {
    #pragma unroll
    for (int i = 0; i < 4; i++){
      #pragma unroll
      for (int j = 0; j < 4; j++){
        int c = (int)nbase + wn*64 + j*16 + lr;
        float bv = bias[c];
        #pragma unroll
        for (int r = 0; r < 4; r++){
          int m = (int)mbase + wm*64 + i*16 + lg*4 + r;
          outF[(long)m * N + c] = acc[i][j][r] + bv;
        }
      }
    }
  }
}

// ---------------- flash attention: per (b,h), Q-tile 64, KV-tile 64 ----------
// q_buf/k_buf/v_buf: [B*H][2048][64] bf16 (q pre-scaled by 0.125)
// o_buf: [8192][1024] bf16  (row b*2048+n, col h*64+d)
__global__ __launch_bounds__(256, 2) void attn_fused(
    const u16* __restrict__ qb, const u16* __restrict__ kb,
    const u16* __restrict__ vb, u16* __restrict__ ob)
{
  __shared__ u16 k_lds[64*64];
  __shared__ u16 vt_lds[64*64];
  __shared__ u16 p_lds[4][16*64];
  const int t = threadIdx.x;
  const int w = t >> 6, l = t & 63, lr = l & 15, lg = l >> 4;
  const int bh = blockIdx.x >> 5;
  const int qt = blockIdx.x & 31;
  const int qrow = qt*64 + w*16;

  const u16* Qp = qb + ((long)bh*2048 + qrow) * 64;
  bf16x8 qf[2];
  qf[0] = *(const bf16x8*)&Qp[lr*64 + lg*8];
  qf[1] = *(const bf16x8*)&Qp[lr*64 + 32 + lg*8];

  float mrun[4], lrun[4];
  f32x4 z = {0.f,0.f,0.f,0.f};
  f32x4 oacc[4];
  #pragma unroll
  for (int r = 0; r < 4; r++){ mrun[r] = -1e30f; lrun[r] = 0.f; }
  #pragma unroll
  for (int nt = 0; nt < 4; nt++) oacc[nt] = z;

  const u16* Kp = kb + (long)bh * 2048 * 64;
  const u16* Vp = vb + (long)bh * 2048 * 64;
  const int sr = t >> 3, sc = (t & 7) * 8;

  for (int kv = 0; kv < 2048; kv += 64){
    __syncthreads();
    // K tile [64k][64d] row-major (direct async copy)
    gload_lds16(Kp + (long)(kv + sr)      * 64 + sc, &k_lds[t*8]);
    gload_lds16(Kp + (long)(kv + 32 + sr) * 64 + sc, &k_lds[2048 + t*8]);
    // V tile transposed to [64d][64k] via registers
    u16x8 v0 = *(const u16x8*)&Vp[(long)(kv + sr)      * 64 + sc];
    u16x8 v1 = *(const u16x8*)&Vp[(long)(kv + 32 + sr) * 64 + sc];
    #pragma unroll
    for (int jj = 0; jj < 8; jj++){
      vt_lds[(sc + jj)*64 + sr]      = v0[jj];
      vt_lds[(sc + jj)*64 + 32 + sr] = v1[jj];
    }
    __syncthreads();

    // S = Q K^T  (q pre-scaled): 4 col-tiles x (K=64 -> 2 mfma)
    f32x4 s[4];
    #pragma unroll
    for (int nt = 0; nt < 4; nt++){
      s[nt] = z;
      #pragma unroll
      for (int kt = 0; kt < 2; kt++){
        bf16x8 kf = *(const bf16x8*)&k_lds[(nt*16 + lr)*64 + kt*32 + lg*8];
        s[nt] = MFMA16(qf[kt], kf, s[nt]);
      }
    }

    // online softmax (rows spread over 16-lane groups)
    float mx[4];
    #pragma unroll
    for (int r = 0; r < 4; r++)
      mx[r] = fmaxf(fmaxf(s[0][r], s[1][r]), fmaxf(s[2][r], s[3][r]));
    #pragma unroll
    for (int msk = 1; msk < 16; msk <<= 1)
      #pragma unroll
      for (int r = 0; r < 4; r++)
        mx[r] = fmaxf(mx[r], __shfl_xor(mx[r], msk, 64));

    float al[4];
    #pragma unroll
    for (int r = 0; r < 4; r++){
      float mn = fmaxf(mrun[r], mx[r]);
      al[r] = __expf(mrun[r] - mn);
      mrun[r] = mn;
    }
    float p[4][4], rs[4];
    #pragma unroll
    for (int nt = 0; nt < 4; nt++)
      #pragma unroll
      for (int r = 0; r < 4; r++)
        p[nt][r] = __expf(s[nt][r] - mrun[r]);
    #pragma unroll
    for (int r = 0; r < 4; r++)
      rs[r] = (p[0][r] + p[1][r]) + (p[2][r] + p[3][r]);
    #pragma unroll
    for (int msk = 1; msk < 16; msk <<= 1)
      #pragma unroll
      for (int r = 0; r < 4; r++)
        rs[r] += __shfl_xor(rs[r], msk, 64);
    #pragma unroll
    for (int r = 0; r < 4; r++)
      lrun[r] = al[r]*lrun[r] + rs[r];
    #pragma unroll
    for (int nt = 0; nt < 4; nt++)
      #pragma unroll
      for (int r = 0; r < 4; r++)
        oacc[nt][r] *= al[r];

    // P -> LDS (bf16), A-fragment friendly layout [q16][k64]
    #pragma unroll
    for (int nt = 0; nt < 4; nt++)
      #pragma unroll
      for (int r = 0; r < 4; r++)
        p_lds[w][(lg*4 + r)*64 + nt*16 + lr] = f2b(p[nt][r]);
    __syncthreads();

    // O += P V
    #pragma unroll
    for (int nt = 0; nt < 4; nt++){
      #pragma unroll
      for (int kt = 0; kt < 2; kt++){
        bf16x8 pf = *(const bf16x8*)&p_lds[w][lr*64 + kt*32 + lg*8];
        bf16x8 vf = *(const bf16x8*)&vt_lds[(nt*16 + lr)*64 + kt*32 + lg*8];
        oacc[nt] = MFMA16(pf, vf, oacc[nt]);
      }
    }
  }

  const int b = bh >> 4, h = bh & 15;
  #pragma unroll
  for (int r = 0; r < 4; r++){
    float inv = 1.0f / lrun[r];
    long m = (long)b*2048 + qrow + lg*4 + r;
    #pragma unroll
    for (int nt = 0; nt < 4; nt++)
      ob[m*1024 + h*64 + nt*16 + lr] = f2b(oacc[nt][r] * inv);
  }
}

extern "C" void kernel_launch(void* const* d_in, const int* in_sizes, int n_in,
                              void* d_out, int out_size, void* d_ws, size_t ws_size,
                              hipStream_t stream)
{
  const float* x      = (const float*)d_in[0];
  const float* w_qkv  = (const float*)d_in[1];
  const float* w_proj = (const float*)d_in[2];
  const float* b_proj = (const float*)d_in[3];
  float* out = (float*)d_out;

  char* ws = (char*)d_ws;
  size_t off = 0;
  // region A: xb (dead after GEMM1) reused as obuf
  u16* xb     = (u16*)(ws + off);                 // 8192*1024 bf16
  u16* obuf   = xb;                               // aliases xb (sequentially dead)
  off += (size_t)8192*1024*2;
  u16* wqkvt  = (u16*)(ws + off); off += (size_t)3072*1024*2;
  u16* wprojt = (u16*)(ws + off); off += (size_t)1024*1024*2;
  u16* qbuf   = (u16*)(ws + off); off += (size_t)64*2048*64*2;
  u16* kbuf   = (u16*)(ws + off); off += (size_t)64*2048*64*2;
  u16* vbuf   = (u16*)(ws + off); off += (size_t)64*2048*64*2;

  cast_f32_bf16<<<2048, 256, 0, stream>>>(x, xb, (8192*1024)/4);
  tcast<<<dim3(96, 32), dim3(32, 8), 0, stream>>>(w_qkv, wqkvt, 1024, 3072);
  tcast<<<dim3(32, 32), dim3(32, 8), 0, stream>>>(w_proj, wprojt, 1024, 1024);

  gemm_bt<0><<<dim3(64, 24), 256, 0, stream>>>(xb, wqkvt, 8192, 3072, 1024,
                                               nullptr, nullptr, qbuf, kbuf, vbuf);
  attn_fused<<<dim3(2048), 256, 0, stream>>>(qbuf, kbuf, vbuf, obuf);
  gemm_bt<1><<<dim3(64, 8), 256, 0, stream>>>(obuf, wprojt, 8192, 1024, 1024,
                                              out, b_proj, nullptr, nullptr, nullptr);
}

// Round 3
// 246.560 us; speedup vs baseline: 1.9471x; 1.9471x over previous
//
#include <hip/hip_runtime.h>

typedef unsigned short u16;
typedef unsigned int   u32;
typedef __attribute__((ext_vector_type(4))) float    f32x4;
typedef __attribute__((ext_vector_type(8))) __bf16   bf16x8;
typedef __attribute__((ext_vector_type(8))) unsigned short u16x8;
typedef __attribute__((ext_vector_type(4))) unsigned short u16x4;
typedef __attribute__((ext_vector_type(4))) float    float4v;

#define MFMA16(a,b,c) __builtin_amdgcn_mfma_f32_16x16x32_bf16((a),(b),(c),0,0,0)

__device__ __forceinline__ u16 f2b(float f){
  union { float f; unsigned u; } v; v.f = f;
  return (u16)((v.u + 0x7fffu + ((v.u >> 16) & 1u)) >> 16);
}

__device__ __forceinline__ u32 cvt_pk_bf16(float lo, float hi){
  u32 r;
  asm("v_cvt_pk_bf16_f32 %0, %1, %2" : "=v"(r) : "v"(lo), "v"(hi));
  return r;
}

__device__ __forceinline__ void gload_lds16(const void* g, void* l){
  __builtin_amdgcn_global_load_lds(
      (const __attribute__((address_space(1))) void*)g,
      (__attribute__((address_space(3))) void*)l, 16, 0, 0);
}

// ---------------- cast fp32 -> bf16 (elementwise, vectorized) ----------------
__global__ void cast_f32_bf16(const float* __restrict__ in, u16* __restrict__ out, int n4){
  int i = blockIdx.x * blockDim.x + threadIdx.x;
  int st = gridDim.x * blockDim.x;
  for (; i < n4; i += st){
    float4v v = ((const float4v*)in)[i];
    u16x4 o;
    o[0] = f2b(v[0]); o[1] = f2b(v[1]); o[2] = f2b(v[2]); o[3] = f2b(v[3]);
    ((u16x4*)out)[i] = o;
  }
}

// ------------- transpose + cast: src fp32 [R][C] -> dst bf16 [C][R] ----------
__global__ void tcast(const float* __restrict__ src, u16* __restrict__ dst, int R, int C){
  __shared__ float tile[32][33];
  int tx = threadIdx.x, ty = threadIdx.y;
  int c0 = blockIdx.x * 32, r0 = blockIdx.y * 32;
  #pragma unroll
  for (int i = 0; i < 4; i++)
    tile[ty + i*8][tx] = src[(long)(r0 + ty + i*8) * C + c0 + tx];
  __syncthreads();
  #pragma unroll
  for (int i = 0; i < 4; i++)
    dst[(long)(c0 + ty + i*8) * R + r0 + tx] = f2b(tile[tx][ty + i*8]);
}

// ------------- bf16 transpose: v [bh][2048][64] -> vt [bh][64][2048] ---------
__global__ void vtrans(const u16* __restrict__ v, u16* __restrict__ vt){
  __shared__ u16 tile[64][72];
  const int t  = threadIdx.x;
  const int bh = blockIdx.x >> 5;
  const int n0 = (blockIdx.x & 31) * 64;
  const u16* src = v + ((long)bh*2048 + n0)*64;
  int rr = t >> 3, cc = (t & 7)*8;
  *(u16x8*)&tile[rr][cc]    = *(const u16x8*)&src[rr*64 + cc];
  *(u16x8*)&tile[rr+32][cc] = *(const u16x8*)&src[(rr+32)*64 + cc];
  __syncthreads();
  u16* dst = vt + ((long)bh*64)*2048 + n0;
  u16x8 o0, o1;
  #pragma unroll
  for (int j = 0; j < 8; j++){ o0[j] = tile[cc + j][rr]; o1[j] = tile[cc + j][rr + 32]; }
  *(u16x8*)&dst[(long)rr*2048 + cc]      = o0;   // fixed: +cc
  *(u16x8*)&dst[(long)(rr+32)*2048 + cc] = o1;   // fixed: +cc
}

// ---------------- bf16 GEMM: C = A[M,K] @ Bt[N,K]^T, 128x128 tile -----------
template<int MODE>
__global__ __launch_bounds__(256, 2) void gemm_bt(
    const u16* __restrict__ A, const u16* __restrict__ Bt,
    int M, int N, int K,
    float* __restrict__ outF, const float* __restrict__ bias,
    u16* __restrict__ qb, u16* __restrict__ kb, u16* __restrict__ vb)
{
  __shared__ u16 a_lds[128*32];
  __shared__ u16 b_lds[128*32];
  const int t  = threadIdx.x;
  const int l  = t & 63;
  const int w  = t >> 6;
  const int wm = w >> 1, wn = w & 1;
  const int lr = l & 15, lg = l >> 4;
  const long mbase = (long)blockIdx.x * 128;
  const long nbase = (long)blockIdx.y * 128;

  f32x4 z = {0.f, 0.f, 0.f, 0.f};
  f32x4 acc[4][4];
  #pragma unroll
  for (int i = 0; i < 4; i++)
    #pragma unroll
    for (int j = 0; j < 4; j++) acc[i][j] = z;

  const int sr = t >> 2;
  const int sc = (t & 3) * 8;
  const u16* Ab = A  + mbase * K;
  const u16* Bb = Bt + nbase * K;

  for (int k0 = 0; k0 < K; k0 += 32){
    __syncthreads();
    gload_lds16(Ab + (long)sr      * K + k0 + sc, &a_lds[t*8]);
    gload_lds16(Ab + (long)(sr+64) * K + k0 + sc, &a_lds[2048 + t*8]);
    gload_lds16(Bb + (long)sr      * K + k0 + sc, &b_lds[t*8]);
    gload_lds16(Bb + (long)(sr+64) * K + k0 + sc, &b_lds[2048 + t*8]);
    __syncthreads();

    bf16x8 af[4], bfr[4];
    #pragma unroll
    for (int i = 0; i < 4; i++)
      af[i] = *(const bf16x8*)&a_lds[(wm*64 + i*16 + lr)*32 + lg*8];
    #pragma unroll
    for (int j = 0; j < 4; j++)
      bfr[j] = *(const bf16x8*)&b_lds[(wn*64 + j*16 + lr)*32 + lg*8];
    #pragma unroll
    for (int i = 0; i < 4; i++)
      #pragma unroll
      for (int j = 0; j < 4; j++)
        acc[i][j] = MFMA16(af[i], bfr[j], acc[i][j]);
  }

  if (MODE == 0){
    #pragma unroll
    for (int i = 0; i < 4; i++){
      #pragma unroll
      for (int j = 0; j < 4; j++){
        int col   = (int)nbase + wn*64 + j*16 + lr;
        int which = col >> 10;
        int h     = (col >> 6) & 15;
        int d     = col & 63;
        u16* dst  = (which == 0) ? qb : ((which == 1) ? kb : vb);
        float scl = (which == 0) ? 0.125f : 1.0f;
        #pragma unroll
        for (int r = 0; r < 4; r++){
          int m  = (int)mbase + wm*64 + i*16 + lg*4 + r;
          int b  = m >> 11, ns = m & 2047;
          dst[((long)((b << 4) + h) * 2048 + ns) * 64 + d] = f2b(acc[i][j][r] * scl);
        }
      }
    }
  } else {
    #pragma unroll
    for (int i = 0; i < 4; i++){
      #pragma unroll
      for (int j = 0; j < 4; j++){
        int c = (int)nbase + wn*64 + j*16 + lr;
        float bv = bias[c];
        #pragma unroll
        for (int r = 0; r < 4; r++){
          int m = (int)mbase + wm*64 + i*16 + lg*4 + r;
          outF[(long)m * N + c] = acc[i][j][r] + bv;
        }
      }
    }
  }
}

// ---------------- flash attention, swapped-QK^T, swizzled LDS ----------------
// qb: [bh][2048][64] bf16 (pre-scaled), kb: [bh][2048][64], vtb: [bh][64][2048]
// ob: [8192][1024] bf16
__global__ __launch_bounds__(256, 4) void attn_fused(
    const u16* __restrict__ qb, const u16* __restrict__ kb,
    const u16* __restrict__ vtb, u16* __restrict__ ob)
{
  __shared__ u16 k_lds[2][64*64];
  __shared__ u16 vt_lds[2][64*64];
  const int t  = threadIdx.x;
  const int l  = t & 63, lr = l & 15, lg = l >> 4;
  const int w  = t >> 6;
  const int bid = blockIdx.x;
  const int vid = (bid & 7) * 256 + (bid >> 3);     // XCD-contiguous
  const int bh = vid >> 5, qt = vid & 31;
  const int qrow = qt*64 + w*16;
  const int h7 = lr & 7;

  // Q fragment (A-layout == B-layout of Q^T)
  const u16* Qp = qb + ((long)bh*2048 + qrow)*64;
  bf16x8 qf0 = *(const bf16x8*)&Qp[lr*64 + lg*8];
  bf16x8 qf1 = *(const bf16x8*)&Qp[lr*64 + 32 + lg*8];

  // staging: LDS[row][chunk x] = G[row][x ^ (row&7)] ; 16B chunks
  const int sr0 = t >> 3;
  const int sx  = t & 7;
  const int c8  = (sx ^ (sr0 & 7)) * 8;
  const u16* Kp = kb  + (long)bh*2048*64;
  const u16* Vt = vtb + (long)bh*64*2048;
  const int koff0 = sr0*64 + c8, koff1 = (sr0+32)*64 + c8;
  const int voff0 = sr0*2048 + c8, voff1 = (sr0+32)*2048 + c8;

#define STAGE(kv, buf) do { \
    gload_lds16(Kp + (long)(kv)*64 + koff0, &k_lds[buf][t*8]); \
    gload_lds16(Kp + (long)(kv)*64 + koff1, &k_lds[buf][2048 + t*8]); \
    gload_lds16(Vt + (kv) + voff0, &vt_lds[buf][t*8]); \
    gload_lds16(Vt + (kv) + voff1, &vt_lds[buf][2048 + t*8]); \
  } while(0)

  f32x4 z = {0.f,0.f,0.f,0.f};
  f32x4 oacc[4] = {z,z,z,z};
  float mrun = -1e30f, lrun = 0.f;   // stats for q-row = lr

  STAGE(0, 0);
  for (int it = 0; it < 32; ++it){
    const int cur = it & 1;
    __syncthreads();                 // buf[cur] ready (barrier drains vmcnt)
    if (it < 31) STAGE((it+1)*64, cur^1);

    const u16* kl = k_lds[cur];
    const u16* vl = vt_lds[cur];

    // S^T tiles: lane holds col q=lr, rows k = k4*16 + lg*4 + r
    f32x4 st[4];
    #pragma unroll
    for (int k4 = 0; k4 < 4; k4++){
      const int row = (k4*16 + lr)*64;
      bf16x8 kf0 = *(const bf16x8*)&kl[row + ((0+lg)^h7)*8];
      bf16x8 kf1 = *(const bf16x8*)&kl[row + ((4+lg)^h7)*8];
      st[k4] = MFMA16(kf0, qf0, z);
      st[k4] = MFMA16(kf1, qf1, st[k4]);
    }

    // online softmax for q = lr
    float mx = st[0][0];
    #pragma unroll
    for (int k4 = 0; k4 < 4; k4++)
      #pragma unroll
      for (int r = 0; r < 4; r++) mx = fmaxf(mx, st[k4][r]);
    mx = fmaxf(mx, __shfl_xor(mx, 16, 64));
    mx = fmaxf(mx, __shfl_xor(mx, 32, 64));

    if (__any(mx > mrun + 8.0f)){    // defer-max
      float mnew = fmaxf(mrun, mx);
      float al = __expf(mrun - mnew);
      mrun = mnew;
      lrun *= al;
      #pragma unroll
      for (int r = 0; r < 4; r++){
        float ar = __shfl(al, lg*4 + r, 64);
        oacc[0][r] *= ar; oacc[1][r] *= ar; oacc[2][r] *= ar; oacc[3][r] *= ar;
      }
    }

    float p[4][4]; float rs = 0.f;
    #pragma unroll
    for (int k4 = 0; k4 < 4; k4++)
      #pragma unroll
      for (int r = 0; r < 4; r++){
        p[k4][r] = __expf(st[k4][r] - mrun);
        rs += p[k4][r];
      }
    rs += __shfl_xor(rs, 16, 64);
    rs += __shfl_xor(rs, 32, 64);
    lrun += rs;

    // pack P pairs; sigma-permuted A-fragment needs NO cross-lane movement:
    // A slot (lg, j) holds logical k = (j>>2)*16 + lg*4 + (j&3)
    u32 wv[4][2];
    #pragma unroll
    for (int k4 = 0; k4 < 4; k4++){
      wv[k4][0] = cvt_pk_bf16(p[k4][0], p[k4][1]);
      wv[k4][1] = cvt_pk_bf16(p[k4][2], p[k4][3]);
    }
    union { u32 u[4]; bf16x8 v; } pa0, pa1;
    pa0.u[0] = wv[0][0]; pa0.u[1] = wv[0][1]; pa0.u[2] = wv[1][0]; pa0.u[3] = wv[1][1];
    pa1.u[0] = wv[2][0]; pa1.u[1] = wv[2][1]; pa1.u[2] = wv[3][0]; pa1.u[3] = wv[3][1];

    // O += P V : B-fragment with same sigma -> 4x b64 reads of V^T per MFMA pair
    const int vhalf = (lg & 1) * 4;    // u16 offset within 16B chunk
    const int cA    = lg >> 1;
    #pragma unroll
    for (int nt = 0; nt < 4; nt++){
      const int rb = (nt*16 + lr)*64;
      u16x4 a0 = *(const u16x4*)&vl[rb + ((cA     ^ h7)*8) + vhalf];  // k: lg*4+0..3
      u16x4 a1 = *(const u16x4*)&vl[rb + (((cA+2) ^ h7)*8) + vhalf];  // k: 16+lg*4+0..3
      u16x4 a2 = *(const u16x4*)&vl[rb + (((cA+4) ^ h7)*8) + vhalf];  // k: 32+lg*4+0..3
      u16x4 a3 = *(const u16x4*)&vl[rb + (((cA+6) ^ h7)*8) + vhalf];  // k: 48+lg*4+0..3
      u16x8 s0 = __builtin_shufflevector(a0, a1, 0,1,2,3,4,5,6,7);
      u16x8 s1 = __builtin_shufflevector(a2, a3, 0,1,2,3,4,5,6,7);
      oacc[nt] = MFMA16(pa0.v, *(bf16x8*)&s0, oacc[nt]);
      oacc[nt] = MFMA16(pa1.v, *(bf16x8*)&s1, oacc[nt]);
    }
  }
#undef STAGE

  float linv = 1.0f / lrun;
  const int b = bh >> 4, h = bh & 15;
  #pragma unroll
  for (int r = 0; r < 4; r++){
    float lrr = __shfl(linv, lg*4 + r, 64);
    long m = (long)b*2048 + qrow + lg*4 + r;
    #pragma unroll
    for (int nt = 0; nt < 4; nt++)
      ob[m*1024 + h*64 + nt*16 + lr] = f2b(oacc[nt][r] * lrr);
  }
}

extern "C" void kernel_launch(void* const* d_in, const int* in_sizes, int n_in,
                              void* d_out, int out_size, void* d_ws, size_t ws_size,
                              hipStream_t stream)
{
  const float* x      = (const float*)d_in[0];
  const float* w_qkv  = (const float*)d_in[1];
  const float* w_proj = (const float*)d_in[2];
  const float* b_proj = (const float*)d_in[3];
  float* out = (float*)d_out;

  char* ws = (char*)d_ws;
  size_t off = 0;
  u16* xb     = (u16*)(ws + off);                 // 16MB, dead after GEMM1
  u16* obuf   = xb;                               // aliases xb
  off += (size_t)8192*1024*2;
  u16* wqkvt  = (u16*)(ws + off); off += (size_t)3072*1024*2;
  u16* wprojt = (u16*)(ws + off); off += (size_t)1024*1024*2;
  u16* qbuf   = (u16*)(ws + off); off += (size_t)64*2048*64*2;
  u16* kbuf   = (u16*)(ws + off); off += (size_t)64*2048*64*2;
  u16* vbuf   = (u16*)(ws + off); off += (size_t)64*2048*64*2;
  u16* vtb    = (u16*)(ws + off); off += (size_t)64*64*2048*2;

  cast_f32_bf16<<<2048, 256, 0, stream>>>(x, xb, (8192*1024)/4);
  tcast<<<dim3(96, 32), dim3(32, 8), 0, stream>>>(w_qkv, wqkvt, 1024, 3072);
  tcast<<<dim3(32, 32), dim3(32, 8), 0, stream>>>(w_proj, wprojt, 1024, 1024);

  gemm_bt<0><<<dim3(64, 24), 256, 0, stream>>>(xb, wqkvt, 8192, 3072, 1024,
                                               nullptr, nullptr, qbuf, kbuf, vbuf);
  vtrans<<<dim3(2048), 256, 0, stream>>>(vbuf, vtb);
  attn_fused<<<dim3(2048), 256, 0, stream>>>(qbuf, kbuf, vtb, obuf);
  gemm_bt<1><<<dim3(64, 8), 256, 0, stream>>>(obuf, wprojt, 8192, 1024, 1024,
                                              out, b_proj, nullptr, nullptr, nullptr);
}